// Round 4
// baseline (70.899 us; speedup 1.0000x reference)
//
#include <hip/hip_runtime.h>
#include <hip/hip_bf16.h>
#include <math.h>

constexpr int IN_F = 128, OUT_F = 256, NH = 4, HD = 64;
constexpr int B = 8, N = 1024;
#define NEG 0.2f

typedef __attribute__((ext_vector_type(8))) short bf16x8;
typedef __attribute__((ext_vector_type(4))) float f32x4;
typedef __attribute__((ext_vector_type(8))) unsigned short u16x8;

static __device__ __forceinline__ short f2bf(float f) {
    __hip_bfloat16 b = __float2bfloat16(f);   // compiler emits v_cvt (m240: beats hand-rolled)
    return *reinterpret_cast<short*>(&b);
}

// ---------------- Kernel 1: h = x @ W  ->  hT (bf16, [B][H][64][N]) + scores ----------------
__global__ __launch_bounds__(256) void k_gemm(
    const float* __restrict__ x,          // [B*N, 128]
    const float* __restrict__ W,          // [128, 256]
    const float* __restrict__ a,          // [128]
    unsigned short* __restrict__ hT,      // [B][H][64][N] bf16 bits (transposed)
    float* __restrict__ siT,              // [B][H][N]
    float* __restrict__ sjT)              // [B][H][N]
{
    constexpr int ROWS = 8;
    __shared__ float xs[ROWS][IN_F];   // 4 KB
    const int t = threadIdx.x;
    const int row0 = blockIdx.x * ROWS;

    ((float4*)xs)[t] = ((const float4*)(x + (size_t)row0 * IN_F))[t];
    __syncthreads();

    float acc[ROWS];
#pragma unroll
    for (int r = 0; r < ROWS; ++r) acc[r] = 0.f;
    for (int k = 0; k < IN_F; ++k) {
        const float w = W[k * OUT_F + t];   // coalesced across t
#pragma unroll
        for (int r = 0; r < ROWS; ++r) acc[r] = fmaf(xs[r][k], w, acc[r]);
    }

    const int lane = t & 63, head = t >> 6, d = t & 63;
    const int b = row0 >> 10, n0 = row0 & (N - 1);

    u16x8 pk;
#pragma unroll
    for (int r = 0; r < ROWS; ++r) pk[r] = (unsigned short)f2bf(acc[r]);
    *(u16x8*)&hT[((size_t)(b * NH + head) * HD + d) * N + n0] = pk;

    const float ai = a[lane], aj = a[HD + lane];
#pragma unroll
    for (int r = 0; r < ROWS; ++r) {
        float si = acc[r] * ai;
        float sj = acc[r] * aj;
#pragma unroll
        for (int off = 32; off; off >>= 1) {
            si += __shfl_xor(si, off, 64);
            sj += __shfl_xor(sj, off, 64);
        }
        if (lane == 0) {
            siT[(size_t)(b * NH + head) * N + n0 + r] = si;
            sjT[(size_t)(b * NH + head) * N + n0 + r] = sj;
        }
    }
}

// ---------------- Kernel 2: MFMA PV, barrier-free j-loop, B-frags straight from L2 ----------------
// grid = B * H * (N/64) = 512 blocks, 256 threads (4 waves). Wave w owns i-rows [i0+16w, i0+16w+16).
// TJ=64: two K=32 MFMA steps per iteration; next iteration's loads prefetched into registers.
__global__ __launch_bounds__(256, 2) void k_pv(
    const unsigned short* __restrict__ hT,   // [B][H][64][N] bf16
    const float* __restrict__ siT,           // [B][H][N]
    const float* __restrict__ sjT,           // [B][H][N]
    const int* __restrict__ adj,             // [B][N][N]
    float* __restrict__ out)                 // [B][N][256]
{
    constexpr int TJ = 64, NIT = N / TJ;
    __shared__ float sjs[N];        // 4 KB
    __shared__ float zbuf[4][16];

    const int bid = blockIdx.x;
    const int itile = bid & 15, h = (bid >> 4) & 3, b = bid >> 6;
    const int t = threadIdx.x, lane = t & 63, w = t >> 6;
    const int i0 = itile * 64 + w * 16;

    ((float4*)sjs)[t] = ((const float4*)(sjT + (size_t)(b * NH + h) * N))[t];

    const int il = lane & 15, q = lane >> 4, qc = q * 8;
    const int i = i0 + il;
    const float si = siT[(size_t)(b * NH + h) * N + i];
    const int4* __restrict__ arow = (const int4*)(adj + ((size_t)b * N + i) * N);
    // lane's B-frag row base: hT[(b,h)] row il, col qc; d-block d adds d*16*N
    const unsigned short* __restrict__ hrow =
        hT + (size_t)(b * NH + h) * HD * N + (size_t)il * N + qc;

    f32x4 acc0 = {0.f,0.f,0.f,0.f}, acc1 = {0.f,0.f,0.f,0.f};
    f32x4 acc2 = {0.f,0.f,0.f,0.f}, acc3 = {0.f,0.f,0.f,0.f};
    float psum = 0.f;

    // ---- prologue: prefetch iteration 0 (independent of sjs)
    bf16x8 cb00 = *(const bf16x8*)(hrow + 0 * 16 * N);
    bf16x8 cb01 = *(const bf16x8*)(hrow + 1 * 16 * N);
    bf16x8 cb02 = *(const bf16x8*)(hrow + 2 * 16 * N);
    bf16x8 cb03 = *(const bf16x8*)(hrow + 3 * 16 * N);
    bf16x8 cb10 = *(const bf16x8*)(hrow + 0 * 16 * N + 32);
    bf16x8 cb11 = *(const bf16x8*)(hrow + 1 * 16 * N + 32);
    bf16x8 cb12 = *(const bf16x8*)(hrow + 2 * 16 * N + 32);
    bf16x8 cb13 = *(const bf16x8*)(hrow + 3 * 16 * N + 32);
    int4 cm00 = arow[qc >> 2];
    int4 cm01 = arow[(qc >> 2) + 1];
    int4 cm10 = arow[(32 + qc) >> 2];
    int4 cm11 = arow[((32 + qc) >> 2) + 1];

    __syncthreads();   // sjs visible (only barrier before epilogue)

    for (int itr = 0; itr < NIT; ++itr) {
        const int j0 = itr * TJ;
        const int jn = (j0 + TJ) & (N - 1);   // wrap on last iter: valid, branch-free

        // ---- prefetch next iteration
        const bf16x8 nb00 = *(const bf16x8*)(hrow + 0 * 16 * N + jn);
        const bf16x8 nb01 = *(const bf16x8*)(hrow + 1 * 16 * N + jn);
        const bf16x8 nb02 = *(const bf16x8*)(hrow + 2 * 16 * N + jn);
        const bf16x8 nb03 = *(const bf16x8*)(hrow + 3 * 16 * N + jn);
        const bf16x8 nb10 = *(const bf16x8*)(hrow + 0 * 16 * N + jn + 32);
        const bf16x8 nb11 = *(const bf16x8*)(hrow + 1 * 16 * N + jn + 32);
        const bf16x8 nb12 = *(const bf16x8*)(hrow + 2 * 16 * N + jn + 32);
        const bf16x8 nb13 = *(const bf16x8*)(hrow + 3 * 16 * N + jn + 32);
        const int4 nm00 = arow[(jn + qc) >> 2];
        const int4 nm01 = arow[((jn + qc) >> 2) + 1];
        const int4 nm10 = arow[(jn + 32 + qc) >> 2];
        const int4 nm11 = arow[((jn + 32 + qc) >> 2) + 1];

        // ---- k-step 0: j = j0 + qc + e
        {
            const int jq = j0 + qc;
            const float4 s0 = *(const float4*)&sjs[jq];
            const float4 s1 = *(const float4*)&sjs[jq + 4];
            const float sv[8] = {s0.x,s0.y,s0.z,s0.w,s1.x,s1.y,s1.z,s1.w};
            const int   mv[8] = {cm00.x,cm00.y,cm00.z,cm00.w,cm01.x,cm01.y,cm01.z,cm01.w};
            bf16x8 af;
#pragma unroll
            for (int e = 0; e < 8; ++e) {
                float ev = si + sv[e];
                ev = (ev >= 0.f) ? ev : NEG * ev;
                const float pe = (mv[e] != 0) ? __expf(ev) : 0.f;
                psum += pe;
                af[e] = f2bf(pe);
            }
            acc0 = __builtin_amdgcn_mfma_f32_16x16x32_bf16(af, cb00, acc0, 0, 0, 0);
            acc1 = __builtin_amdgcn_mfma_f32_16x16x32_bf16(af, cb01, acc1, 0, 0, 0);
            acc2 = __builtin_amdgcn_mfma_f32_16x16x32_bf16(af, cb02, acc2, 0, 0, 0);
            acc3 = __builtin_amdgcn_mfma_f32_16x16x32_bf16(af, cb03, acc3, 0, 0, 0);
        }
        // ---- k-step 1: j = j0 + 32 + qc + e
        {
            const int jq = j0 + 32 + qc;
            const float4 s0 = *(const float4*)&sjs[jq];
            const float4 s1 = *(const float4*)&sjs[jq + 4];
            const float sv[8] = {s0.x,s0.y,s0.z,s0.w,s1.x,s1.y,s1.z,s1.w};
            const int   mv[8] = {cm10.x,cm10.y,cm10.z,cm10.w,cm11.x,cm11.y,cm11.z,cm11.w};
            bf16x8 af;
#pragma unroll
            for (int e = 0; e < 8; ++e) {
                float ev = si + sv[e];
                ev = (ev >= 0.f) ? ev : NEG * ev;
                const float pe = (mv[e] != 0) ? __expf(ev) : 0.f;
                psum += pe;
                af[e] = f2bf(pe);
            }
            acc0 = __builtin_amdgcn_mfma_f32_16x16x32_bf16(af, cb10, acc0, 0, 0, 0);
            acc1 = __builtin_amdgcn_mfma_f32_16x16x32_bf16(af, cb11, acc1, 0, 0, 0);
            acc2 = __builtin_amdgcn_mfma_f32_16x16x32_bf16(af, cb12, acc2, 0, 0, 0);
            acc3 = __builtin_amdgcn_mfma_f32_16x16x32_bf16(af, cb13, acc3, 0, 0, 0);
        }

        // ---- rotate prefetched registers
        cb00 = nb00; cb01 = nb01; cb02 = nb02; cb03 = nb03;
        cb10 = nb10; cb11 = nb11; cb12 = nb12; cb13 = nb13;
        cm00 = nm00; cm01 = nm01; cm10 = nm10; cm11 = nm11;
    }

    // ---- Z[i]: reduce psum over the 4 k-quarter lanes holding the same row
    psum += __shfl_xor(psum, 16, 64);
    psum += __shfl_xor(psum, 32, 64);
    if (lane < 16) zbuf[w][lane] = psum;
    __syncthreads();

    // ---- epilogue: C/D layout col = lane&15, row = q*4 + reg
    float iz[4];
#pragma unroll
    for (int r = 0; r < 4; ++r) iz[r] = 1.f / zbuf[w][q * 4 + r];

    float* __restrict__ ob = out + ((size_t)b * N + i0) * OUT_F + h * HD + il;
#pragma unroll
    for (int r = 0; r < 4; ++r) {
        float* o = ob + (size_t)(q * 4 + r) * OUT_F;
        o[0]  = acc0[r] * iz[r];
        o[16] = acc1[r] * iz[r];
        o[32] = acc2[r] * iz[r];
        o[48] = acc3[r] * iz[r];
    }
}

extern "C" void kernel_launch(void* const* d_in, const int* in_sizes, int n_in,
                              void* d_out, int out_size, void* d_ws, size_t ws_size,
                              hipStream_t stream) {
    const float* x   = (const float*)d_in[0];
    const int*   adj = (const int*)d_in[1];
    const float* W   = (const float*)d_in[2];
    const float* a   = (const float*)d_in[3];
    float* out = (float*)d_out;

    unsigned short* hT = (unsigned short*)d_ws;              // 4 MB bf16
    float* siT = (float*)(hT + (size_t)B * NH * HD * N);     // 128 KB
    float* sjT = siT + (size_t)B * NH * N;                   // 128 KB

    k_gemm<<<B * N / 8, 256, 0, stream>>>(x, W, a, hT, siT, sjT);
    k_pv<<<B * NH * (N / 64), 256, 0, stream>>>(hT, siT, sjT, adj, out);
}

// Round 5
// 64.999 us; speedup vs baseline: 1.0908x; 1.0908x over previous
//
#include <hip/hip_runtime.h>
#include <hip/hip_bf16.h>
#include <math.h>

constexpr int IN_F = 128, OUT_F = 256, NH = 4, HD = 64;
constexpr int B = 8, N = 1024;
#define NEG 0.2f

typedef __attribute__((ext_vector_type(8))) short bf16x8;
typedef __attribute__((ext_vector_type(4))) float f32x4;
typedef __attribute__((ext_vector_type(8))) unsigned short u16x8;

static __device__ __forceinline__ short f2bf(float f) {
    __hip_bfloat16 b = __float2bfloat16(f);
    return *reinterpret_cast<short*>(&b);
}

// ---------------- Kernel 0: bit-pack adjacency (33.5 MB int32 -> 1 MB bits) ----------------
// grid = B*N = 8192 blocks (one row each), 256 threads. Wave w covers j in [256w, 256w+256).
__global__ __launch_bounds__(256) void k_pack(
    const int* __restrict__ adj,                  // [B*N, N]
    unsigned long long* __restrict__ pkd)         // [B*N, 16] bit j -> pkd[row*16 + j/64] bit (j&63)
{
    const int row = blockIdx.x;
    const int t = threadIdx.x, lane = t & 63, wv = t >> 6;
    const int* __restrict__ a = adj + (size_t)row * N + (wv << 8);
#pragma unroll
    for (int c = 0; c < 4; ++c) {
        const int v = a[(c << 6) + lane];         // coalesced 256B per instr
        const unsigned long long m = __ballot(v != 0);
        if (lane == 0) pkd[row * 16 + wv * 4 + c] = m;
    }
}

// ---------------- Kernel 1: h = x @ W  ->  hT (bf16, [B][H][64][N]) + scores ----------------
__global__ __launch_bounds__(256) void k_gemm(
    const float* __restrict__ x,          // [B*N, 128]
    const float* __restrict__ W,          // [128, 256]
    const float* __restrict__ a,          // [128]
    unsigned short* __restrict__ hT,      // [B][H][64][N] bf16 bits (transposed)
    float* __restrict__ siT,              // [B][H][N]
    float* __restrict__ sjT)              // [B][H][N]
{
    constexpr int ROWS = 8;
    __shared__ float xs[ROWS][IN_F];   // 4 KB
    const int t = threadIdx.x;
    const int row0 = blockIdx.x * ROWS;

    ((float4*)xs)[t] = ((const float4*)(x + (size_t)row0 * IN_F))[t];
    __syncthreads();

    float acc[ROWS];
#pragma unroll
    for (int r = 0; r < ROWS; ++r) acc[r] = 0.f;

    // k-chunked: 8 ds_read_b128 per 4 k's (vs 8 ds_read_b32 per k) -- LDS-pipe relief
    for (int k0 = 0; k0 < IN_F; k0 += 4) {
        float4 xr[ROWS];
#pragma unroll
        for (int r = 0; r < ROWS; ++r) xr[r] = *(const float4*)&xs[r][k0];
#pragma unroll
        for (int kk = 0; kk < 4; ++kk) {
            const float w = W[(k0 + kk) * OUT_F + t];   // coalesced, L1/L2-hot
#pragma unroll
            for (int r = 0; r < ROWS; ++r)
                acc[r] = fmaf(((const float*)&xr[r])[kk], w, acc[r]);
        }
    }

    const int lane = t & 63, head = t >> 6, d = t & 63;
    const int b = row0 >> 10, n0 = row0 & (N - 1);

    u16x8 pk;
#pragma unroll
    for (int r = 0; r < ROWS; ++r) pk[r] = (unsigned short)f2bf(acc[r]);
    *(u16x8*)&hT[((size_t)(b * NH + head) * HD + d) * N + n0] = pk;

    const float ai = a[lane], aj = a[HD + lane];
#pragma unroll
    for (int r = 0; r < ROWS; ++r) {
        float si = acc[r] * ai;
        float sj = acc[r] * aj;
#pragma unroll
        for (int off = 32; off; off >>= 1) {
            si += __shfl_xor(si, off, 64);
            sj += __shfl_xor(sj, off, 64);
        }
        if (lane == 0) {
            siT[(size_t)(b * NH + head) * N + n0 + r] = si;
            sjT[(size_t)(b * NH + head) * N + n0 + r] = sj;
        }
    }
}

// ---------------- Kernel 2: MFMA PV; mask from LDS bits; h-frags from L2, reg-prefetched ----------------
// grid = B * H * (N/64) = 512 blocks, 256 threads (4 waves). Wave w owns i-rows [i0+16w, i0+16w+16).
__global__ __launch_bounds__(256, 2) void k_pv(
    const unsigned short* __restrict__ hT,         // [B][H][64][N] bf16
    const float* __restrict__ siT,                 // [B][H][N]
    const float* __restrict__ sjT,                 // [B][H][N]
    const unsigned long long* __restrict__ pkd,    // [B*N, 16] packed adjacency bits
    float* __restrict__ out)                       // [B][N][256]
{
    constexpr int TJ = 64, NIT = N / TJ;
    __shared__ float sjs[N];              // 4 KB
    __shared__ unsigned pwl[32 * 64];     // 8 KB: [word w2 (j/32)][local row] -- conflict-free reads
    __shared__ float zbuf[4][16];

    const int bid = blockIdx.x;
    const int itile = bid & 15, h = (bid >> 4) & 3, b = bid >> 6;
    const int t = threadIdx.x, lane = t & 63, w = t >> 6;
    const int i0 = itile * 64 + w * 16;

    ((float4*)sjs)[t] = ((const float4*)(sjT + (size_t)(b * NH + h) * N))[t];

    // stage packed bits, transposed: thread t -> local row r=t&63, words 8c..8c+7 (c=t>>6)
    {
        const int r = t & 63, c = t >> 6;
        const uint4* pq = (const uint4*)(pkd + ((size_t)b * N + itile * 64 + r) * 16) + c * 2;
        const uint4 w0 = pq[0], w1 = pq[1];
        pwl[(c * 8 + 0) * 64 + r] = w0.x; pwl[(c * 8 + 1) * 64 + r] = w0.y;
        pwl[(c * 8 + 2) * 64 + r] = w0.z; pwl[(c * 8 + 3) * 64 + r] = w0.w;
        pwl[(c * 8 + 4) * 64 + r] = w1.x; pwl[(c * 8 + 5) * 64 + r] = w1.y;
        pwl[(c * 8 + 6) * 64 + r] = w1.z; pwl[(c * 8 + 7) * 64 + r] = w1.w;
    }

    const int il = lane & 15, q = lane >> 4, qc = q * 8;
    const int lr = w * 16 + il;               // local row index into pwl
    const int i = i0 + il;
    const float si = siT[(size_t)(b * NH + h) * N + i];
    const unsigned short* __restrict__ hrow =
        hT + (size_t)(b * NH + h) * HD * N + (size_t)il * N + qc;

    f32x4 acc0 = {0.f,0.f,0.f,0.f}, acc1 = {0.f,0.f,0.f,0.f};
    f32x4 acc2 = {0.f,0.f,0.f,0.f}, acc3 = {0.f,0.f,0.f,0.f};
    float psum = 0.f;

    // prologue: prefetch iteration 0 h-frags
    bf16x8 cb00 = *(const bf16x8*)(hrow + 0 * 16 * N);
    bf16x8 cb01 = *(const bf16x8*)(hrow + 1 * 16 * N);
    bf16x8 cb02 = *(const bf16x8*)(hrow + 2 * 16 * N);
    bf16x8 cb03 = *(const bf16x8*)(hrow + 3 * 16 * N);
    bf16x8 cb10 = *(const bf16x8*)(hrow + 0 * 16 * N + 32);
    bf16x8 cb11 = *(const bf16x8*)(hrow + 1 * 16 * N + 32);
    bf16x8 cb12 = *(const bf16x8*)(hrow + 2 * 16 * N + 32);
    bf16x8 cb13 = *(const bf16x8*)(hrow + 3 * 16 * N + 32);

    __syncthreads();   // sjs + pwl visible

    for (int itr = 0; itr < NIT; ++itr) {
        const int j0 = itr * TJ;
        const int jn = (j0 + TJ) & (N - 1);   // wrap on last iter: valid, branch-free

        // prefetch next iteration's h-frags (L2-hot)
        const bf16x8 nb00 = *(const bf16x8*)(hrow + 0 * 16 * N + jn);
        const bf16x8 nb01 = *(const bf16x8*)(hrow + 1 * 16 * N + jn);
        const bf16x8 nb02 = *(const bf16x8*)(hrow + 2 * 16 * N + jn);
        const bf16x8 nb03 = *(const bf16x8*)(hrow + 3 * 16 * N + jn);
        const bf16x8 nb10 = *(const bf16x8*)(hrow + 0 * 16 * N + jn + 32);
        const bf16x8 nb11 = *(const bf16x8*)(hrow + 1 * 16 * N + jn + 32);
        const bf16x8 nb12 = *(const bf16x8*)(hrow + 2 * 16 * N + jn + 32);
        const bf16x8 nb13 = *(const bf16x8*)(hrow + 3 * 16 * N + jn + 32);

        // ---- k-step 0: j = j0 + qc + e
        {
            const unsigned byte = (pwl[(2 * itr + 0) * 64 + lr] >> qc) & 0xffu;
            const int jq = j0 + qc;
            const float4 s0 = *(const float4*)&sjs[jq];
            const float4 s1 = *(const float4*)&sjs[jq + 4];
            const float sv[8] = {s0.x,s0.y,s0.z,s0.w,s1.x,s1.y,s1.z,s1.w};
            bf16x8 af;
#pragma unroll
            for (int e = 0; e < 8; ++e) {
                float ev = si + sv[e];
                ev = (ev >= 0.f) ? ev : NEG * ev;
                const float pe = ((byte >> e) & 1u) ? __expf(ev) : 0.f;
                psum += pe;
                af[e] = f2bf(pe);
            }
            acc0 = __builtin_amdgcn_mfma_f32_16x16x32_bf16(af, cb00, acc0, 0, 0, 0);
            acc1 = __builtin_amdgcn_mfma_f32_16x16x32_bf16(af, cb01, acc1, 0, 0, 0);
            acc2 = __builtin_amdgcn_mfma_f32_16x16x32_bf16(af, cb02, acc2, 0, 0, 0);
            acc3 = __builtin_amdgcn_mfma_f32_16x16x32_bf16(af, cb03, acc3, 0, 0, 0);
        }
        // ---- k-step 1: j = j0 + 32 + qc + e
        {
            const unsigned byte = (pwl[(2 * itr + 1) * 64 + lr] >> qc) & 0xffu;
            const int jq = j0 + 32 + qc;
            const float4 s0 = *(const float4*)&sjs[jq];
            const float4 s1 = *(const float4*)&sjs[jq + 4];
            const float sv[8] = {s0.x,s0.y,s0.z,s0.w,s1.x,s1.y,s1.z,s1.w};
            bf16x8 af;
#pragma unroll
            for (int e = 0; e < 8; ++e) {
                float ev = si + sv[e];
                ev = (ev >= 0.f) ? ev : NEG * ev;
                const float pe = ((byte >> e) & 1u) ? __expf(ev) : 0.f;
                psum += pe;
                af[e] = f2bf(pe);
            }
            acc0 = __builtin_amdgcn_mfma_f32_16x16x32_bf16(af, cb10, acc0, 0, 0, 0);
            acc1 = __builtin_amdgcn_mfma_f32_16x16x32_bf16(af, cb11, acc1, 0, 0, 0);
            acc2 = __builtin_amdgcn_mfma_f32_16x16x32_bf16(af, cb12, acc2, 0, 0, 0);
            acc3 = __builtin_amdgcn_mfma_f32_16x16x32_bf16(af, cb13, acc3, 0, 0, 0);
        }

        // rotate prefetched registers
        cb00 = nb00; cb01 = nb01; cb02 = nb02; cb03 = nb03;
        cb10 = nb10; cb11 = nb11; cb12 = nb12; cb13 = nb13;
    }

    // Z[i]: reduce psum over the 4 k-quarter lanes holding the same row
    psum += __shfl_xor(psum, 16, 64);
    psum += __shfl_xor(psum, 32, 64);
    if (lane < 16) zbuf[w][lane] = psum;
    __syncthreads();

    // epilogue: C/D layout col = lane&15, row = q*4 + reg
    float iz[4];
#pragma unroll
    for (int r = 0; r < 4; ++r) iz[r] = 1.f / zbuf[w][q * 4 + r];

    float* __restrict__ ob = out + ((size_t)b * N + i0) * OUT_F + h * HD + il;
#pragma unroll
    for (int r = 0; r < 4; ++r) {
        float* o = ob + (size_t)(q * 4 + r) * OUT_F;
        o[0]  = acc0[r] * iz[r];
        o[16] = acc1[r] * iz[r];
        o[32] = acc2[r] * iz[r];
        o[48] = acc3[r] * iz[r];
    }
}

extern "C" void kernel_launch(void* const* d_in, const int* in_sizes, int n_in,
                              void* d_out, int out_size, void* d_ws, size_t ws_size,
                              hipStream_t stream) {
    const float* x   = (const float*)d_in[0];
    const int*   adj = (const int*)d_in[1];
    const float* W   = (const float*)d_in[2];
    const float* a   = (const float*)d_in[3];
    float* out = (float*)d_out;

    unsigned short* hT = (unsigned short*)d_ws;                        // 4 MB bf16
    float* siT = (float*)(hT + (size_t)B * NH * HD * N);               // 128 KB
    float* sjT = siT + (size_t)B * NH * N;                             // 128 KB
    unsigned long long* pkd = (unsigned long long*)(sjT + (size_t)B * NH * N);   // 1 MB

    k_pack<<<B * N, 256, 0, stream>>>(adj, pkd);
    k_gemm<<<B * N / 8, 256, 0, stream>>>(x, W, a, hT, siT, sjT);
    k_pv<<<B * NH * (N / 64), 256, 0, stream>>>(hT, siT, sjT, pkd, out);
}